// Round 4
// baseline (15152.580 us; speedup 1.0000x reference)
//
#include <hip/hip_runtime.h>
#include <stdint.h>
#include <stddef.h>

#define TT 1024
#define BB 64
#define HH 1024
#define II 1024

typedef __attribute__((ext_vector_type(8))) short s16x8;
typedef __attribute__((ext_vector_type(4))) float f32x4;

// ---- workspace layout (bytes) ----
// 0      : claim[8] u32      (per-XCD arrival tickets, agent atomics)
// 64     : arrived  u32
// 512    : flags[8][64] u32  (per group: words 0..7 used; 256 B stride)
// 4096   : ring PURE:   g*32768 + slot*16384 + row*2048 + feat*2   (8g,2s,8r,1024f)
// 266240 : ring IMPURE: same geometry (disjoint addresses; write-through only)
#define WS_CLAIM   0
#define WS_ARRIVED 64
#define WS_FLAGS   512
#define WS_RING_P  4096
#define WS_RING_I  266240

static __device__ __forceinline__ unsigned short f2bf(float f) {
    union { float f; unsigned int u; } v; v.f = f;
    return (unsigned short)((v.u + 0x7fffu + ((v.u >> 16) & 1u)) >> 16);
}

static __device__ __forceinline__ s16x8 pack8(float4 a, float4 b) {
    s16x8 v;
    v[0] = (short)f2bf(a.x); v[1] = (short)f2bf(a.y);
    v[2] = (short)f2bf(a.z); v[3] = (short)f2bf(a.w);
    v[4] = (short)f2bf(b.x); v[5] = (short)f2bf(b.y);
    v[6] = (short)f2bf(b.z); v[7] = (short)f2bf(b.w);
    return v;
}

static __device__ __forceinline__ f32x4 zero4() {
    f32x4 v = {0.f, 0.f, 0.f, 0.f};
    return v;
}

// Pure (same-XCD) path: sc0 = L1-bypass, served/cached by the local L2.
static __device__ __forceinline__ s16x8 ld16_sc0(const void* p) {
    s16x8 v;
    asm volatile("global_load_dwordx4 %0, %1, off sc0" : "=v"(v) : "v"(p));
    return v;
}
// Impure (cross-XCD) path: sc0 sc1 = bypass to device coherence point.
static __device__ __forceinline__ s16x8 ld16_sc01(const void* p) {
    s16x8 v;
    asm volatile("global_load_dwordx4 %0, %1, off sc0 sc1" : "=v"(v) : "v"(p));
    return v;
}
static __device__ __forceinline__ void st_h(void* p, unsigned short val, int pure) {
    unsigned v32 = val;
    if (pure)
        asm volatile("global_store_short %0, %1, off sc0" :: "v"(p), "v"(v32) : "memory");
    else
        asm volatile("global_store_short %0, %1, off sc0 sc1" :: "v"(p), "v"(v32) : "memory");
}
#define WAITV(n) do { asm volatile("s_waitcnt vmcnt(" #n ")" ::: "memory"); \
                      __builtin_amdgcn_sched_barrier(0); } while (0)

// ---------------------------------------------------------------------------
// Kernel 0: zero claim/arrived/flags via AGENT ATOMIC stores (keeps these
// lines out of any L2 as dirty data; scan accesses them only via atomics).
// ---------------------------------------------------------------------------
__global__ void init_ws(unsigned int* w) {
    for (int i = threadIdx.x; i < 640; i += 256)
        __hip_atomic_store(&w[i], 0u, __ATOMIC_RELAXED, __HIP_MEMORY_SCOPE_AGENT);
}

// ---------------------------------------------------------------------------
// Kernel 1: xw = x @ W_ih^T + b_ih + b_hh -> d_out states area (unchanged).
// ---------------------------------------------------------------------------
__global__ __launch_bounds__(256, 2) void xw_gemm(
    const float* __restrict__ X,
    const float* __restrict__ Wih,
    const float* __restrict__ bih,
    const float* __restrict__ bhh,
    float* __restrict__ out)
{
    __shared__ unsigned short As[128 * 64];
    __shared__ unsigned short Bs[128 * 64];

    const int tid  = threadIdx.x;
    const int lane = tid & 63;
    const int wid  = tid >> 6;
    const int bm = blockIdx.x >> 3;
    const int bn = blockIdx.x & 7;
    const size_t m0 = (size_t)bm * 128;
    const int n0 = bn * 128;
    const int wm = (wid >> 1) * 64;
    const int wn = (wid & 1) * 64;

    f32x4 acc[4][4];
#pragma unroll
    for (int i = 0; i < 4; ++i)
#pragma unroll
        for (int jj = 0; jj < 4; ++jj) acc[i][jj] = zero4();

    const int srow  = tid >> 1;
    const int shalf = tid & 1;
    const float* xp = X   + (m0 + srow) * (size_t)II + shalf * 32;
    const float* wp = Wih + (size_t)(n0 + srow) * II + shalf * 32;

    for (int kt = 0; kt < II / 64; ++kt) {
#pragma unroll
        for (int i = 0; i < 4; ++i) {
            float4 a0 = *(const float4*)(xp + i * 8);
            float4 a1 = *(const float4*)(xp + i * 8 + 4);
            float4 b0 = *(const float4*)(wp + i * 8);
            float4 b1 = *(const float4*)(wp + i * 8 + 4);
            const int c = shalf * 4 + i;
            const int cw = (c ^ (srow & 7)) << 3;
            *(s16x8*)&As[srow * 64 + cw] = pack8(a0, a1);
            *(s16x8*)&Bs[srow * 64 + cw] = pack8(b0, b1);
        }
        __syncthreads();

#pragma unroll
        for (int kk = 0; kk < 2; ++kk) {
            s16x8 af[4], bf[4];
            const int cs = kk * 4 + (lane >> 4);
#pragma unroll
            for (int mi = 0; mi < 4; ++mi) {
                const int r = wm + mi * 16 + (lane & 15);
                af[mi] = *(const s16x8*)&As[r * 64 + ((cs ^ (r & 7)) << 3)];
            }
#pragma unroll
            for (int ni = 0; ni < 4; ++ni) {
                const int r = wn + ni * 16 + (lane & 15);
                bf[ni] = *(const s16x8*)&Bs[r * 64 + ((cs ^ (r & 7)) << 3)];
            }
#pragma unroll
            for (int mi = 0; mi < 4; ++mi)
#pragma unroll
                for (int ni = 0; ni < 4; ++ni)
                    acc[mi][ni] = __builtin_amdgcn_mfma_f32_16x16x32_bf16(
                        af[mi], bf[ni], acc[mi][ni], 0, 0, 0);
        }
        __syncthreads();
        xp += 64; wp += 64;
    }

#pragma unroll
    for (int ni = 0; ni < 4; ++ni) {
        const int col = n0 + wn + ni * 16 + (lane & 15);
        const float bias = bih[col] + bhh[col];
#pragma unroll
        for (int mi = 0; mi < 4; ++mi) {
            const size_t row = m0 + wm + mi * 16 + ((lane >> 4) << 2);
#pragma unroll
            for (int r = 0; r < 4; ++r)
                out[(row + r) * (size_t)HH + col] = acc[mi][ni][r] + bias;
        }
    }
}

#define STEP4(cg, n) do { \
    asm volatile("s_waitcnt vmcnt(" #n ")" ::: "memory"); \
    __builtin_amdgcn_sched_barrier(0); \
    acc[0] = __builtin_amdgcn_mfma_f32_16x16x32_bf16(ab[4*(cg)+0], bfr[4*(cg)+0], acc[0], 0, 0, 0); \
    acc[1] = __builtin_amdgcn_mfma_f32_16x16x32_bf16(ab[4*(cg)+1], bfr[4*(cg)+1], acc[1], 0, 0, 0); \
    acc[2] = __builtin_amdgcn_mfma_f32_16x16x32_bf16(ab[4*(cg)+2], bfr[4*(cg)+2], acc[2], 0, 0, 0); \
    acc[3] = __builtin_amdgcn_mfma_f32_16x16x32_bf16(ab[4*(cg)+3], bfr[4*(cg)+3], acc[3], 0, 0, 0); \
} while (0)

// ---------------------------------------------------------------------------
// Kernel 2: persistent scan. 64 blocks x 512 thr (8 waves). XCD election:
// blocks claim a slot on their own XCD (agent atomics, one-time, 64-block
// co-residency proven in round 1); (group, rank, pure) derived from claim
// prefix sums identically in every block. 8 groups x 8 batch rows x 8 blocks
// (rank = 128-feature slice). Pure group => sc0 ring (local-L2 multicast);
// impure => sc0sc1 ring in a disjoint region (round-3 semantics). Flags:
// per-block, agent atomics, 1 line per group. W in 128 VGPR/wave; A-frag
// rows 8..15 duplicate rows 0..7 (epilogue masks kg>=2). No LDS in loop.
// ---------------------------------------------------------------------------
__global__ __launch_bounds__(512, 1) void rnn_scan(
    const float* __restrict__ Whh,
    float* __restrict__ out,
    void* __restrict__ ws)
{
    __shared__ int meta[4];
    const int tid  = threadIdx.x;
    const int lane = tid & 63;
    const int wid  = tid >> 6;

    if (tid == 0) {
        unsigned xcd;
        asm volatile("s_getreg_b32 %0, hwreg(HW_REG_XCC_ID)" : "=s"(xcd));
        xcd &= 7u;
        unsigned* claim   = (unsigned*)((char*)ws + WS_CLAIM);
        unsigned* arrived = (unsigned*)((char*)ws + WS_ARRIVED);
        unsigned myslot = __hip_atomic_fetch_add(&claim[xcd], 1u, __ATOMIC_RELAXED,
                                                 __HIP_MEMORY_SCOPE_AGENT);
        __hip_atomic_fetch_add(arrived, 1u, __ATOMIC_RELEASE,
                               __HIP_MEMORY_SCOPE_AGENT);
        while (__hip_atomic_load(arrived, __ATOMIC_RELAXED,
                                 __HIP_MEMORY_SCOPE_AGENT) < 64u)
            __builtin_amdgcn_s_sleep(8);
        (void)__hip_atomic_load(arrived, __ATOMIC_ACQUIRE, __HIP_MEMORY_SCOPE_AGENT);
        unsigned cl[8];
#pragma unroll
        for (int i = 0; i < 8; ++i)
            cl[i] = __hip_atomic_load(&claim[i], __ATOMIC_RELAXED,
                                      __HIP_MEMORY_SCOPE_AGENT);
        unsigned cum = 0;
        for (int x = 0; x < (int)xcd; ++x) cum += cl[x];
        const int p = (int)(cum + myslot);
        const int g = p >> 3, rank = p & 7;
        int pure = 0; cum = 0;
        for (int x = 0; x < 8; ++x) {
            if (cum <= (unsigned)(g * 8) && (unsigned)(g * 8 + 8) <= cum + cl[x])
                pure = 1;
            cum += cl[x];
        }
        meta[0] = g; meta[1] = rank; meta[2] = pure;
    }
    __syncthreads();
    const int g = meta[0], rank = meta[1], pure = meta[2];

    // ---- one-time: this wave's 16 W_hh rows -> 128 VGPRs of B-fragments ----
    const int j  = rank * 128 + wid * 16 + (lane & 15);  // output feature
    const int kg = lane >> 4;                             // k-quadrant
    s16x8 bfr[32];
    {
        const float* wr = Whh + (size_t)j * HH + kg * 8;
#pragma unroll
        for (int c = 0; c < 32; ++c) {
            float4 p0 = *(const float4*)(wr + c * 32);
            float4 p1 = *(const float4*)(wr + c * 32 + 4);
            bfr[c] = pack8(p0, p1);
        }
    }

    unsigned* fl = (unsigned*)((char*)ws + WS_FLAGS) + g * 64;
    char* region = (char*)ws + (pure ? WS_RING_P : WS_RING_I) + (size_t)g * 32768;
    const char* pa0 = region + (lane & 7) * 2048 + kg * 16;  // slot 0 A base
    const char* pa1 = pa0 + 16384;                            // slot 1 A base

    const int kgm = kg & 1;           // epilogue row-block (kg>=2 masked out)
    float hprev[4] = {0.f, 0.f, 0.f, 0.f};

    // ---- t = 0: h = tanh(xw); hr_1 = 0.5*h -> slot 1 ----
    if (kg < 2) {
#pragma unroll
        for (int r = 0; r < 4; ++r) {
            const int b = g * 8 + kg * 4 + r;
            const size_t idx = ((size_t)b * TT) * HH + j;
            const float h = tanhf(out[idx]);
            out[idx] = h;
            hprev[r] = h;
            st_h(region + 16384 + (kg * 4 + r) * 2048 + j * 2, f2bf(0.5f * h), pure);
        }
    }
    asm volatile("s_waitcnt vmcnt(0)" ::: "memory");
    __syncthreads();
    if (tid == 0)
        __hip_atomic_store(&fl[rank], 1u, __ATOMIC_RELAXED, __HIP_MEMORY_SCOPE_AGENT);

#pragma unroll 1
    for (int t = 1; t < TT; ++t) {
        // ---- xw prefetch: issued now, lands during the first poll iter ----
        float xwv[4]; size_t xidx[4];
#pragma unroll
        for (int r = 0; r < 4; ++r) {
            const int b = g * 8 + kgm * 4 + r;
            xidx[r] = ((size_t)b * TT + t) * HH + j;
            xwv[r] = out[xidx[r]];
        }

        // ---- poll the group's 8 per-block flags (one cache line) ----
        {
            const unsigned* myp = fl + (lane & 7);
            for (;;) {
                unsigned v = __hip_atomic_load(myp, __ATOMIC_RELAXED,
                                               __HIP_MEMORY_SCOPE_AGENT);
                if (__all((int)(v >= (unsigned)t))) break;
                __builtin_amdgcn_s_sleep(1);
            }
            asm volatile("" ::: "memory");
            __builtin_amdgcn_sched_barrier(0);
        }

        // ---- 32 pipelined A-loads + 32 MFMA (counted vmcnt) ----
        const char* p = (t & 1) ? pa1 : pa0;
        s16x8 ab[32];
        if (pure) {
#pragma unroll
            for (int c = 0; c < 32; ++c) { ab[c] = ld16_sc0(p); p += 64; }
        } else {
#pragma unroll
            for (int c = 0; c < 32; ++c) { ab[c] = ld16_sc01(p); p += 64; }
        }
        f32x4 acc[4];
#pragma unroll
        for (int i = 0; i < 4; ++i) acc[i] = zero4();
        STEP4(0, 28); STEP4(1, 24); STEP4(2, 20); STEP4(3, 16);
        STEP4(4, 12); STEP4(5, 8);  STEP4(6, 4);  STEP4(7, 0);

        f32x4 accT = acc[0] + acc[1] + acc[2] + acc[3];

        // ---- epilogue: tanh, states, hr_{t+1}, publish ----
        char* rw = region + (size_t)((t + 1) & 1) * 16384;
        if (kg < 2) {
#pragma unroll
            for (int r = 0; r < 4; ++r) {
                const float h = tanhf(accT[r] + xwv[r]);
                out[xidx[r]] = h;
                if (t == TT - 1)
                    out[(size_t)BB * TT * HH +
                        (size_t)(g * 8 + kg * 4 + r) * HH + j] = h;
                else
                    st_h(rw + (kg * 4 + r) * 2048 + j * 2,
                         f2bf(0.5f * (h + hprev[r])), pure);
                hprev[r] = h;
            }
        }
        if (t < TT - 1) {
            asm volatile("s_waitcnt vmcnt(0)" ::: "memory");
            __syncthreads();
            if (tid == 0)
                __hip_atomic_store(&fl[rank], (unsigned)(t + 1),
                                   __ATOMIC_RELAXED, __HIP_MEMORY_SCOPE_AGENT);
        }
    }
}

// ---------------------------------------------------------------------------
extern "C" void kernel_launch(void* const* d_in, const int* in_sizes, int n_in,
                              void* d_out, int out_size, void* d_ws, size_t ws_size,
                              hipStream_t stream)
{
    const float* X   = (const float*)d_in[0];
    const float* Wih = (const float*)d_in[1];
    const float* Whh = (const float*)d_in[2];
    const float* bih = (const float*)d_in[3];
    const float* bhh = (const float*)d_in[4];
    float* out = (float*)d_out;

    init_ws<<<dim3(1), dim3(256), 0, stream>>>((unsigned int*)d_ws);
    xw_gemm<<<dim3(4096), dim3(256), 0, stream>>>(X, Wih, bih, bhh, out);
    rnn_scan<<<dim3(64), dim3(512), 0, stream>>>(Whh, out, d_ws);
}

// Round 5
// 3810.835 us; speedup vs baseline: 3.9762x; 3.9762x over previous
//
#include <hip/hip_runtime.h>
#include <stdint.h>
#include <stddef.h>

#define TT 1024
#define BB 64
#define HH 1024
#define II 1024

typedef __attribute__((ext_vector_type(8))) short s16x8;
typedef __attribute__((ext_vector_type(4))) float f32x4;

// ---- workspace layout (bytes) ----
// 512  : flags[4][64] u32   (per group: words 0..15 used; 256 B stride)
// 4096 : ring: group*65536 + slot*32768 + row*2048 + feat*2
//        (4 groups, 2 slots, 16 rows, 1024 bf16 features)
#define WS_FLAGS 512
#define WS_RING  4096

static __device__ __forceinline__ unsigned short f2bf(float f) {
    union { float f; unsigned int u; } v; v.f = f;
    return (unsigned short)((v.u + 0x7fffu + ((v.u >> 16) & 1u)) >> 16);
}

static __device__ __forceinline__ s16x8 pack8(float4 a, float4 b) {
    s16x8 v;
    v[0] = (short)f2bf(a.x); v[1] = (short)f2bf(a.y);
    v[2] = (short)f2bf(a.z); v[3] = (short)f2bf(a.w);
    v[4] = (short)f2bf(b.x); v[5] = (short)f2bf(b.y);
    v[6] = (short)f2bf(b.z); v[7] = (short)f2bf(b.w);
    return v;
}

static __device__ __forceinline__ f32x4 zero4() {
    f32x4 v = {0.f, 0.f, 0.f, 0.f};
    return v;
}

// Device-coherent-point access (round-3-proven): sc0 sc1 = bypass L1+L2.
static __device__ __forceinline__ s16x8 ld16_sc01(const void* p) {
    s16x8 v;
    asm volatile("global_load_dwordx4 %0, %1, off sc0 sc1" : "=v"(v) : "v"(p));
    return v;
}
static __device__ __forceinline__ void st_h(void* p, unsigned short val) {
    unsigned v32 = val;
    asm volatile("global_store_short %0, %1, off sc0 sc1" :: "v"(p), "v"(v32) : "memory");
}
#define WAITV(n) do { asm volatile("s_waitcnt vmcnt(" #n ")" ::: "memory"); \
                      __builtin_amdgcn_sched_barrier(0); } while (0)

// ---------------------------------------------------------------------------
// Kernel 0: zero the control region (flags) each launch.
// ---------------------------------------------------------------------------
__global__ void init_ws(unsigned int* w) {
    for (int i = threadIdx.x; i < 640; i += 256)
        __hip_atomic_store(&w[i], 0u, __ATOMIC_RELAXED, __HIP_MEMORY_SCOPE_AGENT);
}

// ---------------------------------------------------------------------------
// Kernel 1: xw = x @ W_ih^T + b_ih + b_hh -> d_out states area (unchanged).
// ---------------------------------------------------------------------------
__global__ __launch_bounds__(256, 2) void xw_gemm(
    const float* __restrict__ X,
    const float* __restrict__ Wih,
    const float* __restrict__ bih,
    const float* __restrict__ bhh,
    float* __restrict__ out)
{
    __shared__ unsigned short As[128 * 64];
    __shared__ unsigned short Bs[128 * 64];

    const int tid  = threadIdx.x;
    const int lane = tid & 63;
    const int wid  = tid >> 6;
    const int bm = blockIdx.x >> 3;
    const int bn = blockIdx.x & 7;
    const size_t m0 = (size_t)bm * 128;
    const int n0 = bn * 128;
    const int wm = (wid >> 1) * 64;
    const int wn = (wid & 1) * 64;

    f32x4 acc[4][4];
#pragma unroll
    for (int i = 0; i < 4; ++i)
#pragma unroll
        for (int jj = 0; jj < 4; ++jj) acc[i][jj] = zero4();

    const int srow  = tid >> 1;
    const int shalf = tid & 1;
    const float* xp = X   + (m0 + srow) * (size_t)II + shalf * 32;
    const float* wp = Wih + (size_t)(n0 + srow) * II + shalf * 32;

    for (int kt = 0; kt < II / 64; ++kt) {
#pragma unroll
        for (int i = 0; i < 4; ++i) {
            float4 a0 = *(const float4*)(xp + i * 8);
            float4 a1 = *(const float4*)(xp + i * 8 + 4);
            float4 b0 = *(const float4*)(wp + i * 8);
            float4 b1 = *(const float4*)(wp + i * 8 + 4);
            const int c = shalf * 4 + i;
            const int cw = (c ^ (srow & 7)) << 3;
            *(s16x8*)&As[srow * 64 + cw] = pack8(a0, a1);
            *(s16x8*)&Bs[srow * 64 + cw] = pack8(b0, b1);
        }
        __syncthreads();

#pragma unroll
        for (int kk = 0; kk < 2; ++kk) {
            s16x8 af[4], bf[4];
            const int cs = kk * 4 + (lane >> 4);
#pragma unroll
            for (int mi = 0; mi < 4; ++mi) {
                const int r = wm + mi * 16 + (lane & 15);
                af[mi] = *(const s16x8*)&As[r * 64 + ((cs ^ (r & 7)) << 3)];
            }
#pragma unroll
            for (int ni = 0; ni < 4; ++ni) {
                const int r = wn + ni * 16 + (lane & 15);
                bf[ni] = *(const s16x8*)&Bs[r * 64 + ((cs ^ (r & 7)) << 3)];
            }
#pragma unroll
            for (int mi = 0; mi < 4; ++mi)
#pragma unroll
                for (int ni = 0; ni < 4; ++ni)
                    acc[mi][ni] = __builtin_amdgcn_mfma_f32_16x16x32_bf16(
                        af[mi], bf[ni], acc[mi][ni], 0, 0, 0);
        }
        __syncthreads();
        xp += 64; wp += 64;
    }

#pragma unroll
    for (int ni = 0; ni < 4; ++ni) {
        const int col = n0 + wn + ni * 16 + (lane & 15);
        const float bias = bih[col] + bhh[col];
#pragma unroll
        for (int mi = 0; mi < 4; ++mi) {
            const size_t row = m0 + wm + mi * 16 + ((lane >> 4) << 2);
#pragma unroll
            for (int r = 0; r < 4; ++r)
                out[(row + r) * (size_t)HH + col] = acc[mi][ni][r] + bias;
        }
    }
}

// ---------------------------------------------------------------------------
// Kernel 2: persistent scan. 64 blocks x 256 thr (4 waves). 4 groups x 16
// blocks; group g owns batch rows [16g,16g+16); block = 64 features. W in
// 128 VGPR/wave. Per step: poll 16 per-BLOCK flags (agent relaxed atomics,
// one line) -> cooperative 32 KB hr stage (sc0sc1, line-coalesced, ONCE per
// block) into XOR-swizzled LDS -> __syncthreads -> 32x(ds_read_b128+MFMA)
// per wave -> tanh -> states + hr_{t+1} (sc0sc1) -> vmcnt(0) -> syncthreads
// -> publish block flag. No L2 flush/invalidate, no placement assumptions.
// ---------------------------------------------------------------------------
__global__ __launch_bounds__(256, 1) void rnn_scan(
    const float* __restrict__ Whh,
    float* __restrict__ out,
    void* __restrict__ ws)
{
    __shared__ unsigned short Hl[16 * 1024];   // 32 KiB staged hr tile

    const int tid  = threadIdx.x;
    const int lane = tid & 63;
    const int wid  = tid >> 6;
    const int g  = blockIdx.x >> 4;     // 0..3 batch group
    const int sl = blockIdx.x & 15;     // 0..15 feature slice (64 feats)

    const int j  = sl * 64 + wid * 16 + (lane & 15);  // output feature
    const int kg = lane >> 4;                          // k-quadrant (0..3)

    // ---- one-time: this wave's 16 W_hh rows -> 128 VGPRs of B-fragments ----
    s16x8 bfr[32];
    {
        const float* wr = Whh + (size_t)j * HH + kg * 8;
#pragma unroll
        for (int c = 0; c < 32; ++c) {
            float4 p0 = *(const float4*)(wr + c * 32);
            float4 p1 = *(const float4*)(wr + c * 32 + 4);
            bfr[c] = pack8(p0, p1);
        }
    }

    unsigned* fl = (unsigned*)((char*)ws + WS_FLAGS) + g * 64;
    char* rg = (char*)ws + WS_RING + (size_t)g * 65536;

    // staging role: thread stages row (tid>>4), 16B segment (tid&15) + i*256
    const int srow = tid >> 4;
    const int sseg = tid & 15;
    const char* sbase0 = rg + srow * 2048 + sseg * 16;           // slot 0
    const char* sbase1 = sbase0 + 32768;                          // slot 1

    const int arow = lane & 15;        // A row for fragment reads
    const int brow = kg * 4;           // C rows kg*4 .. kg*4+3
    float hprev[4];

    // ---- t = 0: h = tanh(xw); hr_1 = 0.5*h -> slot 1 ----
#pragma unroll
    for (int r = 0; r < 4; ++r) {
        const int b = g * 16 + brow + r;
        const size_t idx = ((size_t)b * TT) * HH + j;
        const float h = tanhf(out[idx]);
        out[idx] = h;
        hprev[r] = h;
        st_h(rg + 32768 + (brow + r) * 2048 + j * 2, f2bf(0.5f * h));
    }
    asm volatile("s_waitcnt vmcnt(0)" ::: "memory");
    __syncthreads();
    if (tid == 0)
        __hip_atomic_store(&fl[sl], 1u, __ATOMIC_RELAXED, __HIP_MEMORY_SCOPE_AGENT);

#pragma unroll 1
    for (int t = 1; t < TT; ++t) {
        // ---- xw prefetch: issued now, lands while we poll ----
        float xwv[4]; size_t xidx[4];
#pragma unroll
        for (int r = 0; r < 4; ++r) {
            const int b = g * 16 + brow + r;
            xidx[r] = ((size_t)b * TT + t) * HH + j;
            xwv[r] = out[xidx[r]];
        }

        // ---- poll the group's 16 per-block flags (one line) ----
        {
            const unsigned* myp = fl + (lane & 15);
            for (;;) {
                unsigned v = __hip_atomic_load(myp, __ATOMIC_RELAXED,
                                               __HIP_MEMORY_SCOPE_AGENT);
                if (__all((int)(v >= (unsigned)t))) break;
                __builtin_amdgcn_s_sleep(1);
            }
            asm volatile("" ::: "memory");
            __builtin_amdgcn_sched_barrier(0);
        }

        // ---- cooperative stage: 32 KB tile, once per block, coalesced ----
        {
            const char* sp = (t & 1) ? sbase1 : sbase0;
            s16x8 v[8];
#pragma unroll
            for (int i = 0; i < 8; ++i) v[i] = ld16_sc01(sp + i * 256);
#pragma unroll
            for (int i = 0; i < 8; ++i) {
                if (i == 0)      { WAITV(7); }
                else if (i == 1) { WAITV(6); }
                else if (i == 2) { WAITV(5); }
                else if (i == 3) { WAITV(4); }
                else if (i == 4) { WAITV(3); }
                else if (i == 5) { WAITV(2); }
                else if (i == 6) { WAITV(1); }
                else             { WAITV(0); }
                const int c = sseg + i * 16;                  // chunk 0..127
                *(s16x8*)&Hl[srow * 1024 + ((c ^ (srow & 7)) << 3)] = v[i];
            }
        }
        __syncthreads();

        // ---- 32 x (ds_read_b128 A + MFMA with VGPR B) ----
        f32x4 acc[4];
#pragma unroll
        for (int i = 0; i < 4; ++i) acc[i] = zero4();
#pragma unroll
        for (int kb = 0; kb < 4; ++kb) {
            s16x8 a8[8];
#pragma unroll
            for (int ki = 0; ki < 8; ++ki) {
                const int cs = (kb * 8 + ki) * 4 + kg;
                a8[ki] = *(const s16x8*)&Hl[arow * 1024 + ((cs ^ (arow & 7)) << 3)];
            }
#pragma unroll
            for (int ki = 0; ki < 8; ++ki)
                acc[ki & 3] = __builtin_amdgcn_mfma_f32_16x16x32_bf16(
                    a8[ki], bfr[kb * 8 + ki], acc[ki & 3], 0, 0, 0);
        }
        f32x4 accT = acc[0] + acc[1] + acc[2] + acc[3];

        // ---- epilogue: tanh, states, hr_{t+1}, publish ----
        char* rw = rg + (size_t)((t + 1) & 1) * 32768;
#pragma unroll
        for (int r = 0; r < 4; ++r) {
            const float h = tanhf(accT[r] + xwv[r]);
            out[xidx[r]] = h;
            if (t == TT - 1)
                out[(size_t)BB * TT * HH +
                    (size_t)(g * 16 + brow + r) * HH + j] = h;
            else
                st_h(rw + (brow + r) * 2048 + j * 2, f2bf(0.5f * (h + hprev[r])));
            hprev[r] = h;
        }
        if (t < TT - 1) {
            asm volatile("s_waitcnt vmcnt(0)" ::: "memory");
            __syncthreads();   // all waves' ring stores drained; LDS reads done
            if (tid == 0)
                __hip_atomic_store(&fl[sl], (unsigned)(t + 1),
                                   __ATOMIC_RELAXED, __HIP_MEMORY_SCOPE_AGENT);
        }
    }
}

// ---------------------------------------------------------------------------
extern "C" void kernel_launch(void* const* d_in, const int* in_sizes, int n_in,
                              void* d_out, int out_size, void* d_ws, size_t ws_size,
                              hipStream_t stream)
{
    const float* X   = (const float*)d_in[0];
    const float* Wih = (const float*)d_in[1];
    const float* Whh = (const float*)d_in[2];
    const float* bih = (const float*)d_in[3];
    const float* bhh = (const float*)d_in[4];
    float* out = (float*)d_out;

    init_ws<<<dim3(1), dim3(256), 0, stream>>>((unsigned int*)d_ws);
    xw_gemm<<<dim3(4096), dim3(256), 0, stream>>>(X, Wih, bih, bhh, out);
    rnn_scan<<<dim3(64), dim3(256), 0, stream>>>(Whh, out, d_ws);
}